// Round 1
// baseline (1013.354 us; speedup 1.0000x reference)
//
#include <hip/hip_runtime.h>
#include <cstddef>

#define NB 16
#define NS 8192
#define NH 1024
#define INV_SCALE 0.03125f   // 1/sqrt(1024)

// ---------------------------------------------------------------------------
// Kernel 1: tq[b,i] = sum_j q[b,j] * W[i,j]   (tq = q @ W^T)
// One 64-lane wave per output element; float4-coalesced row dot.
// grid = NB*NH/4 blocks of 256 threads (4 waves/block).
// ---------------------------------------------------------------------------
__global__ void tq_kernel(const float* __restrict__ q,
                          const float* __restrict__ W,
                          float* __restrict__ tq) {
    int wave = blockIdx.x * 4 + (threadIdx.x >> 6);
    int lane = threadIdx.x & 63;
    int b = wave >> 10;           // / NH
    int i = wave & (NH - 1);
    const float4* q4 = reinterpret_cast<const float4*>(q + (size_t)b * NH);
    const float4* w4 = reinterpret_cast<const float4*>(W + (size_t)i * NH);
    float acc = 0.f;
#pragma unroll
    for (int k = 0; k < 4; ++k) {
        float4 a = q4[lane + k * 64];
        float4 w = w4[lane + k * 64];
        acc += a.x * w.x + a.y * w.y + a.z * w.z + a.w * w.w;
    }
#pragma unroll
    for (int off = 32; off > 0; off >>= 1) acc += __shfl_down(acc, off, 64);
    if (lane == 0) tq[wave] = acc;
}

// ---------------------------------------------------------------------------
// Kernel 2: scores[b,s] = dot(tq[b], keys[b,s]) * INV_SCALE, masked to -1e9.
// One wave per (b,s). Reads the 512 MiB keys tensor exactly once, coalesced.
// grid = NB*NS/4 blocks of 256 threads.
// ---------------------------------------------------------------------------
__global__ void scores_kernel(const float* __restrict__ tq,
                              const float* __restrict__ keys,
                              const int* __restrict__ mask,
                              float* __restrict__ scores) {
    int wave = blockIdx.x * 4 + (threadIdx.x >> 6);
    int lane = threadIdx.x & 63;
    int b = wave >> 13;           // / NS
    int s = wave & (NS - 1);
    const float4* t4 = reinterpret_cast<const float4*>(tq + (size_t)b * NH);
    const float4* k4 = reinterpret_cast<const float4*>(keys + ((size_t)b * NS + s) * NH);
    float acc = 0.f;
#pragma unroll
    for (int k = 0; k < 4; ++k) {
        float4 a = t4[lane + k * 64];
        float4 kk = k4[lane + k * 64];
        acc += a.x * kk.x + a.y * kk.y + a.z * kk.z + a.w * kk.w;
    }
#pragma unroll
    for (int off = 32; off > 0; off >>= 1) acc += __shfl_down(acc, off, 64);
    if (lane == 0) {
        float v = acc * INV_SCALE;
        if (mask[(size_t)b * NS + s] == 0) v = -1e9f;
        scores[(size_t)b * NS + s] = v;
    }
}

// ---------------------------------------------------------------------------
// Kernel 3: in-place softmax over S for each batch row.
// One block of 1024 threads per batch; each thread owns 2 float4 (8 elems).
// ---------------------------------------------------------------------------
__global__ void softmax_kernel(float* __restrict__ attn) {
    int b = blockIdx.x;
    int tid = threadIdx.x;        // 0..1023
    float4* row4 = reinterpret_cast<float4*>(attn + (size_t)b * NS);
    __shared__ float red[16];
    __shared__ float bc;

    float4 a = row4[tid];
    float4 c = row4[tid + 1024];

    float m = fmaxf(fmaxf(fmaxf(a.x, a.y), fmaxf(a.z, a.w)),
                    fmaxf(fmaxf(c.x, c.y), fmaxf(c.z, c.w)));
#pragma unroll
    for (int off = 32; off > 0; off >>= 1) m = fmaxf(m, __shfl_down(m, off, 64));
    if ((tid & 63) == 0) red[tid >> 6] = m;
    __syncthreads();
    if (tid == 0) {
        float mm = red[0];
        for (int i = 1; i < 16; ++i) mm = fmaxf(mm, red[i]);
        bc = mm;
    }
    __syncthreads();
    m = bc;

    a.x = expf(a.x - m); a.y = expf(a.y - m); a.z = expf(a.z - m); a.w = expf(a.w - m);
    c.x = expf(c.x - m); c.y = expf(c.y - m); c.z = expf(c.z - m); c.w = expf(c.w - m);
    float sum = a.x + a.y + a.z + a.w + c.x + c.y + c.z + c.w;
#pragma unroll
    for (int off = 32; off > 0; off >>= 1) sum += __shfl_down(sum, off, 64);
    __syncthreads();              // all reads of bc(max) done before reuse
    if ((tid & 63) == 0) red[tid >> 6] = sum;
    __syncthreads();
    if (tid == 0) {
        float ss = 0.f;
        for (int i = 0; i < 16; ++i) ss += red[i];
        bc = 1.f / ss;
    }
    __syncthreads();
    float inv = bc;

    a.x *= inv; a.y *= inv; a.z *= inv; a.w *= inv;
    c.x *= inv; c.y *= inv; c.z *= inv; c.w *= inv;
    row4[tid] = a;
    row4[tid + 1024] = c;
}

// ---------------------------------------------------------------------------
// Kernel 4: partial context. grid = NB*split blocks, 256 threads.
// Block (b,chunk) accumulates rows s0..s0+rows-1: each thread owns one float4
// (4 h's, covering all H=1024). Reads the 512 MiB values tensor once.
// ---------------------------------------------------------------------------
__global__ void ctx_partial_kernel(const float* __restrict__ attn,
                                   const float* __restrict__ values,
                                   float* __restrict__ partial,
                                   int split, int rows) {
    int blk = blockIdx.x;
    int b = blk / split;
    int chunk = blk - b * split;
    int s0 = chunk * rows;
    int tid = threadIdx.x;
    const float4* v4 = reinterpret_cast<const float4*>(values + ((size_t)b * NS + s0) * NH);
    const float* arow = attn + (size_t)b * NS + s0;
    float4 acc = make_float4(0.f, 0.f, 0.f, 0.f);
    for (int s = 0; s < rows; ++s) {
        float w = arow[s];
        float4 v = v4[(size_t)s * 256 + tid];
        acc.x += w * v.x; acc.y += w * v.y; acc.z += w * v.z; acc.w += w * v.w;
    }
    reinterpret_cast<float4*>(partial)[(size_t)blk * 256 + tid] = acc;
}

// Reduce partials: ctx[b,h] = sum_c partial[b,c,h]. grid = NB, 1024 threads.
__global__ void ctx_reduce_kernel(const float* __restrict__ partial,
                                  float* __restrict__ ctx, int split) {
    int b = blockIdx.x;
    int tid = threadIdx.x;        // h index
    const float* base = partial + ((size_t)b * split) * NH + tid;
    float acc = 0.f;
    for (int c = 0; c < split; ++c) acc += base[(size_t)c * NH];
    ctx[(size_t)b * NH + tid] = acc;
}

// ---- fallback path (only if ws too small for partials): atomic accumulate --
__global__ void ctx_zero_kernel(float* __restrict__ ctx) {
    ctx[blockIdx.x * 256 + threadIdx.x] = 0.f;
}
__global__ void ctx_atomic_kernel(const float* __restrict__ attn,
                                  const float* __restrict__ values,
                                  float* __restrict__ ctx,
                                  int split, int rows) {
    int blk = blockIdx.x;
    int b = blk / split;
    int chunk = blk - b * split;
    int s0 = chunk * rows;
    int tid = threadIdx.x;
    const float4* v4 = reinterpret_cast<const float4*>(values + ((size_t)b * NS + s0) * NH);
    const float* arow = attn + (size_t)b * NS + s0;
    float4 acc = make_float4(0.f, 0.f, 0.f, 0.f);
    for (int s = 0; s < rows; ++s) {
        float w = arow[s];
        float4 v = v4[(size_t)s * 256 + tid];
        acc.x += w * v.x; acc.y += w * v.y; acc.z += w * v.z; acc.w += w * v.w;
    }
    float* dst = ctx + (size_t)b * NH + 4 * tid;
    atomicAdd(dst + 0, acc.x);
    atomicAdd(dst + 1, acc.y);
    atomicAdd(dst + 2, acc.z);
    atomicAdd(dst + 3, acc.w);
}

extern "C" void kernel_launch(void* const* d_in, const int* in_sizes, int n_in,
                              void* d_out, int out_size, void* d_ws, size_t ws_size,
                              hipStream_t stream) {
    const float* q      = (const float*)d_in[0];
    const float* keys   = (const float*)d_in[1];
    const float* values = (const float*)d_in[2];
    const int*   mask   = (const int*)d_in[3];
    const float* W      = (const float*)d_in[4];

    float* out  = (float*)d_out;
    float* ctx  = out;                 // [B,H]  context, first in tuple
    float* attn = out + NB * NH;       // [B,S]  attention weights, second

    float* tq      = (float*)d_ws;               // NB*NH floats = 64 KB
    float* partial = tq + NB * NH;               // up to NB*128*NH floats = 8 MB

    // 1) tq = q @ W^T
    tq_kernel<<<NB * NH / 4, 256, 0, stream>>>(q, W, tq);
    // 2) masked, scaled scores -> attn region of d_out
    scores_kernel<<<NB * NS / 4, 256, 0, stream>>>(tq, keys, mask, attn);
    // 3) softmax in place
    softmax_kernel<<<NB, 1024, 0, stream>>>(attn);

    // 4) context = attn @ values, split over S for parallelism
    size_t tq_bytes = (size_t)NB * NH * sizeof(float);
    size_t avail = ws_size > tq_bytes ? ws_size - tq_bytes : 0;
    int split = 0;
    for (int s2 = 128; s2 >= 2; s2 >>= 1) {
        if ((size_t)s2 * NB * NH * sizeof(float) <= avail) { split = s2; break; }
    }
    if (split >= 2) {
        int rows = NS / split;
        ctx_partial_kernel<<<NB * split, 256, 0, stream>>>(attn, values, partial, split, rows);
        ctx_reduce_kernel<<<NB, 1024, 0, stream>>>(partial, ctx, split);
    } else {
        // ws too small: zero the context then atomically accumulate
        ctx_zero_kernel<<<NB * NH / 256, 256, 0, stream>>>(ctx);
        ctx_atomic_kernel<<<NB * 64, 256, 0, stream>>>(attn, values, ctx, 64, NS / 64);
    }
}